// Round 1
// baseline (148.599 us; speedup 1.0000x reference)
//
#include <hip/hip_runtime.h>
#include <math.h>

#define T_STEPS 730
#define NB      1000
#define LENF    15
#define NEARZ   1e-5f
#define TPAD    736            // per-lane row stride (floats); 730 rounded to x16B
#define NLANES  8000           // 1000 basins x 8 members (chains)
#define NTHR    4000           // 2 chains per lane (R11): (b,m) and (b,m+4)

// ===========================================================================
// PASS A: serial S/G state recurrence only.
// R11: occupancy 1.2%/VALUBusy 4% showed each of the 125 waves sat alone on
// its SIMD, stalled ~2/3 of cycles on the S-chain (sqrt/exp2 latency).  HW
// can't co-schedule a 2nd wave per SIMD at 125 waves/1024 SIMDs, so we
// interleave TWO independent chains per lane -> chain1's issue fills
// chain0's dependency stalls.  Forcing (p,pet) is shared (same basin).
// Per step/lane: 26 VALU physics + 1 store + ~1 prefetch; dep chain ~40-60cy
// -> ~60-70 cy/step vs ~150 before.
// Stores: 16-deep register rings, dwordx4 every 4 steps, per-lane rows with
// compile-time byte offsets (reuse distance 12+ steps: no vmcnt stall on
// data-reg reuse).
// ===========================================================================
#define STEP2(CURV, Q, SIDX)                                                   \
  {                                                                            \
    float pcp = (CURV).x, pet = (CURV).y;                                      \
    float W0    = pcp + S0;                                                    \
    float W1    = pcp + S1;                                                    \
    float term0 = fmaf(W0, inv2a0, pb2a0);                                     \
    float term1 = fmaf(W1, inv2a1, pb2a1);                                     \
    float disc0 = fmaf(term0, term0, -(W0 * boa0));                            \
    float disc1 = fmaf(term1, term1, -(W1 * boa1));                            \
    float r0    = __builtin_amdgcn_sqrtf(fmaxf(disc0, NEARZ));                 \
    float r1    = __builtin_amdgcn_sqrtf(fmaxf(disc1, NEARZ));                 \
    float Y0    = term0 - r0;                                                  \
    float Y1    = term1 - r1;                                                  \
    float e0    = __builtin_amdgcn_exp2f(pet * nbl0);                          \
    float e1    = __builtin_amdgcn_exp2f(pet * nbl1);                          \
    float Sn0   = Y0 * e0;                                                     \
    float Sn1   = Y1 * e1;                                                     \
    float av0   = W0 - Y0;                                                     \
    float av1   = W1 - Y1;                                                     \
    float Gn0   = fmaf(pc0, av0, G0) * i1d0;                                   \
    float Gn1   = fmaf(pc1, av1, G1) * i1d1;                                   \
    S0 = Sn0; G0 = Gn0; S1 = Sn1; G1 = Gn1;                                    \
    sr0[(Q)] = Sn0; gr0[(Q)] = Gn0;                                            \
    sr1[(Q)] = Sn1; gr1[(Q)] = Gn1;                                            \
    if (((Q) & 3) == 3 && act) {                                               \
      *(float4*)(pS0 + (SIDX) - 3) =                                           \
          make_float4(sr0[(Q) - 3], sr0[(Q) - 2], sr0[(Q) - 1], sr0[(Q)]);     \
      *(float4*)(pG0 + (SIDX) - 3) =                                           \
          make_float4(gr0[(Q) - 3], gr0[(Q) - 2], gr0[(Q) - 1], gr0[(Q)]);     \
      *(float4*)(pS1 + (SIDX) - 3) =                                           \
          make_float4(sr1[(Q) - 3], sr1[(Q) - 2], sr1[(Q) - 1], sr1[(Q)]);     \
      *(float4*)(pG1 + (SIDX) - 3) =                                           \
          make_float4(gr1[(Q) - 3], gr1[(Q) - 2], gr1[(Q) - 1], gr1[(Q)]);     \
    }                                                                          \
  }

#define PREFETCH(BUF, CI)                                                      \
  _Pragma("unroll")                                                            \
  for (int j = 0; j < 8; ++j) {                                                \
      int tt = (CI) * 8 + j;                                                   \
      tt = tt < T_STEPS ? tt : (T_STEPS - 1);                                  \
      BUF[j] = xf[tt * NB + b];                                                \
  }                                                                            \
  __builtin_amdgcn_sched_barrier(0);

__global__ __launch_bounds__(64, 1) void scan_state(const float* __restrict__ x,
                                                    const float* __restrict__ raw,
                                                    float* __restrict__ snp,
                                                    float* __restrict__ gnp) {
    const int L   = threadIdx.x;
    const int gid = blockIdx.x * 64 + L;      // 0..4031 (grid=63)
    const bool act = gid < NTHR;
    const int b   = act ? (gid >> 2) : (NB - 1);  // clamp: OOB lanes load valid, store nothing
    const int m0  = gid & 3;                  // chain0 = m0, chain1 = m0+4

    // raw layout (B,34) = [a(8), b(8), c(8), d(8), ra, rb]
    const float* rp = raw + b * 34;
    float pa0 = rp[0 * 8 + m0] * 0.9f + 0.1f;
    float pb0 = rp[1 * 8 + m0] * 450.0f + 50.0f;
    float pc0 = rp[2 * 8 + m0];
    float pd0 = rp[3 * 8 + m0] * 0.89f + 0.01f;
    float pa1 = rp[0 * 8 + m0 + 4] * 0.9f + 0.1f;
    float pb1 = rp[1 * 8 + m0 + 4] * 450.0f + 50.0f;
    float pc1 = rp[2 * 8 + m0 + 4];
    float pd1 = rp[3 * 8 + m0 + 4] * 0.89f + 0.01f;

    float inv2a0 = 1.0f / (2.0f * pa0);
    float pb2a0  = pb0 * inv2a0;
    float boa0   = pb0 / pa0;
    float nbl0   = -1.4426950408889634f / pb0;   // exp(-pet/b)=exp2(pet*this)
    float i1d0   = 1.0f / (1.0f + pd0);
    float inv2a1 = 1.0f / (2.0f * pa1);
    float pb2a1  = pb1 * inv2a1;
    float boa1   = pb1 / pa1;
    float nbl1   = -1.4426950408889634f / pb1;
    float i1d1   = 1.0f / (1.0f + pd1);

    float* pS0 = snp + (size_t)(b * 8 + m0) * TPAD;      // 16B-aligned rows
    float* pG0 = gnp + (size_t)(b * 8 + m0) * TPAD;
    float* pS1 = snp + (size_t)(b * 8 + m0 + 4) * TPAD;
    float* pG1 = gnp + (size_t)(b * 8 + m0 + 4) * TPAD;

    float S0 = 50.0f, G0 = 10.0f;
    float S1 = 50.0f, G1 = 10.0f;
    float sr0[16], gr0[16], sr1[16], gr1[16];

    const float2* __restrict__ xf = (const float2*)x;   // (T,B) of (p,pet)

    float2 A[8], Bb[8], Cc[8];
    PREFETCH(A, 0)
    PREFETCH(Bb, 1)

    // 15 groups x 48 steps (6 chunks of 8; 48 % 16 == 0 keeps ring phase
    // static across groups) = 720 steps, + 10-step tail.
    for (int g = 0; g < 15; ++g) {
        const int c0 = 6 * g;
        PREFETCH(Cc, c0 + 2)
#pragma unroll
        for (int j = 0; j < 8; ++j) STEP2(A[j],  j,      j)
        PREFETCH(A, c0 + 3)
#pragma unroll
        for (int j = 0; j < 8; ++j) STEP2(Bb[j], 8 + j,  8 + j)
        PREFETCH(Bb, c0 + 4)
#pragma unroll
        for (int j = 0; j < 8; ++j) STEP2(Cc[j], j,      16 + j)
        PREFETCH(Cc, c0 + 5)
#pragma unroll
        for (int j = 0; j < 8; ++j) STEP2(A[j],  8 + j,  24 + j)
        PREFETCH(A, c0 + 6)
#pragma unroll
        for (int j = 0; j < 8; ++j) STEP2(Bb[j], j,      32 + j)
        PREFETCH(Bb, c0 + 7)
#pragma unroll
        for (int j = 0; j < 8; ++j) STEP2(Cc[j], 8 + j,  40 + j)
        pS0 += 48; pG0 += 48; pS1 += 48; pG1 += 48;
    }
    // tail: A = chunk 90 (t=720..727), Bb = clamped chunk 91 (Bb[0]=728, Bb[1]=729)
#pragma unroll
    for (int j = 0; j < 8; ++j) STEP2(A[j], j, j)
    STEP2(Bb[0], 8, 8)
    STEP2(Bb[1], 9, 9)
    if (act) {
        *(float2*)(pS0 + 8) = make_float2(sr0[8], sr0[9]);
        *(float2*)(pG0 + 8) = make_float2(gr0[8], gr0[9]);
        *(float2*)(pS1 + 8) = make_float2(sr1[8], sr1[9]);
        *(float2*)(pG1 + 8) = make_float2(gr1[8], gr1[9]);
    }
}

// ===========================================================================
// PASS B: t-parallel finalize. Block = 256 threads = one (t-tile, basin);
// grid = (3, 1000). Reconstructs Y = Sn*exp2(+pet/b) (exact inverse of pass
// A's factor), computes all 5 cross-member means, writes ch3..5, stages
// qs/qg sums in LDS (270 = 256 + 14 halo), then 15-tap gamma-UH conv
// (weights inline; 0.125 ensemble mean folded in) -> ch0..2.
// ===========================================================================
__global__ __launch_bounds__(256) void finalize(const float* __restrict__ x,
                                                const float* __restrict__ raw,
                                                const float* __restrict__ snp,
                                                const float* __restrict__ gnp,
                                                float* __restrict__ out) {
    __shared__ float qs_sh[270], qg_sh[270];

    const int b     = blockIdx.y;
    const int tbase = blockIdx.x * 256;
    const int tid   = threadIdx.x;

    // per-member derived params (block-uniform loads -> broadcast)
    const float* rp = raw + b * 34;
    float e2s[8], omc_[8], d_[8];
#pragma unroll
    for (int m = 0; m < 8; ++m) {
        float pb = rp[8 + m] * 450.0f + 50.0f;
        e2s[m]  = 1.4426950408889634f / pb;     // Y = Sn * exp2(pet * e2s)
        omc_[m] = 1.0f - rp[16 + m];
        d_[m]   = rp[24 + m] * 0.89f + 0.01f;
    }

    const float2* __restrict__ xf = (const float2*)x;

    // ---- compute phase: 270 t-values (tile + 14-step halo) ----------------
#pragma unroll
    for (int it = 0; it < 2; ++it) {
        int idx = tid + it * 256;
        if (idx < 270) {
            int tt = tbase + idx - 14;
            float qs = 0.0f, qg = 0.0f;
            if (tt >= 0 && tt < T_STEPS) {
                float2 pc2 = xf[tt * NB + b];
                float p = pc2.x, pet = pc2.y;
                float aet = 0.0f, ssum = 0.0f, gsum = 0.0f;
                int tprev = tt > 0 ? tt - 1 : 0;
#pragma unroll
                for (int m = 0; m < 8; ++m) {
                    const float* rowS = snp + (size_t)(b * 8 + m) * TPAD;
                    const float* rowG = gnp + (size_t)(b * 8 + m) * TPAD;
                    float sn = rowS[tt];
                    float sp = tt > 0 ? rowS[tprev] : 50.0f;
                    float gn = rowG[tt];
                    float y  = sn * __builtin_amdgcn_exp2f(pet * e2s[m]);
                    float avail = (p + sp) - y;
                    qs   += omc_[m] * avail;
                    qg   += d_[m] * gn;
                    aet  += y - sn;
                    ssum += sn;
                    gsum += gn;
                }
                if (idx >= 14) {   // own tile only (halo owned by prev block)
                    float* o = out + ((size_t)tt * NB + b) * 6;
                    o[3] = aet * 0.125f;
                    o[4] = ssum * 0.125f;
                    o[5] = gsum * 0.125f;
                }
            }
            qs_sh[idx] = qs;       // zero for tt<0 (block 0 halo) / tt>=T
            qg_sh[idx] = qg;
        }
    }
    __syncthreads();

    // ---- conv phase: gamma-UH weights (gammaln cancels under norm) --------
    const int t = tbase + tid;
    if (t >= T_STEPS) return;

    float ra = rp[32] * 2.9f;
    float rb = rp[33] * 6.5f;
    float aa = fmaxf(ra, 0.0f) + 0.1f;
    float th = fmaxf(rb, 0.0f) + 0.5f;
    float inv_th = 1.0f / th;
    float am1 = aa - 1.0f;
    float w[LENF];
    float sw = 0.0f;
#pragma unroll
    for (int k = 0; k < LENF; ++k) {
        float tk = (float)k + 0.5f;
        w[k] = __expf(am1 * __logf(tk) - tk * inv_th);
        sw += w[k];
    }
    float invs = 0.125f / sw;      // UH normalization x ensemble mean
    float ys = 0.0f, yg = 0.0f;
#pragma unroll
    for (int k = 0; k < LENF; ++k) {
        float wk = w[k] * invs;
        ys = fmaf(qs_sh[tid + 14 - k], wk, ys);
        yg = fmaf(qg_sh[tid + 14 - k], wk, yg);
    }
    float* o = out + ((size_t)t * NB + b) * 6;
    o[0] = ys + yg;
    o[1] = ys;
    o[2] = yg;
}

// ===========================================================================
// FALLBACK (ws too small for the 47MB state planes): R8's proven path.
// ===========================================================================
template <int CTRL>
__device__ __forceinline__ float dpp_mov(float x) {
    int xi = __builtin_bit_cast(int, x);
    int r  = __builtin_amdgcn_update_dpp(0, xi, CTRL, 0xF, 0xF, true);
    return __builtin_bit_cast(float, r);
}
__device__ __forceinline__ float sum8(float v) {
    v += dpp_mov<0xB1>(v);
    v += dpp_mov<0x4E>(v);
    v += dpp_mov<0x141>(v);
    return v;
}

#define STEPF(CURV)                                                            \
  {                                                                            \
    float pcp = (CURV).x, pet = (CURV).y;                                      \
    float W     = pcp + S;                                                     \
    float term  = fmaf(W, inv2a, pb2a);                                        \
    float disc  = fmaf(term, term, -(W * boa));                                \
    float r     = __builtin_amdgcn_sqrtf(fmaxf(disc, NEARZ));                  \
    float Y     = term - r;                                                    \
    float e     = __builtin_amdgcn_exp2f(pet * ninvbl2);                       \
    float Sn    = Y * e;                                                       \
    float AET   = Y - Sn;                                                      \
    float avail = W - Y;                                                       \
    float Qs    = omc * avail;                                                 \
    float Gn    = fmaf(pc, avail, G) * inv1pd;                                 \
    float Qg    = pd * Gn;                                                     \
    S = Sn; G = Gn;                                                            \
    float qs_s = sum8(Qs);                                                     \
    float qg_s = sum8(Qg);                                                     \
    float ae_s = sum8(AET);                                                    \
    float s_s  = sum8(Sn);                                                     \
    float g_s  = sum8(Gn);                                                     \
    float v = qs_s;                                                            \
    v = (m == 1) ? qg_s : v;                                                   \
    v = (m == 2) ? ae_s : v;                                                   \
    v = (m == 3) ? s_s  : v;                                                   \
    v = (m >= 4) ? g_s  : v;                                                   \
    *optr = v * 0.125f;                                                        \
    optr += incr;                                                              \
  }

__global__ __launch_bounds__(64, 1) void scan_fb(const float* __restrict__ x,
                                                 const float* __restrict__ raw,
                                                 float* __restrict__ out,
                                                 float* __restrict__ qs_ws,
                                                 float* __restrict__ qg_ws,
                                                 float* __restrict__ dummy) {
    const int L  = threadIdx.x;
    const int lb = L >> 3;
    const int m  = L & 7;
    const int b  = blockIdx.x * 8 + lb;

    const float* rp = raw + b * 34;
    float pa = rp[0 * 8 + m] * 0.9f + 0.1f;
    float pb = rp[1 * 8 + m] * 450.0f + 50.0f;
    float pc = rp[2 * 8 + m];
    float pd = rp[3 * 8 + m] * 0.89f + 0.01f;
    float inv2a   = 1.0f / (2.0f * pa);
    float pb2a    = pb * inv2a;
    float boa     = pb / pa;
    float ninvbl2 = -1.4426950408889634f / pb;
    float omc     = 1.0f - pc;
    float inv1pd  = 1.0f / (1.0f + pd);

    float* optr;
    long long incr;
    if      (m == 0) { optr = qs_ws + b;                      incr = NB;     }
    else if (m == 1) { optr = qg_ws + b;                      incr = NB;     }
    else if (m <= 4) { optr = out + (long long)b * 6 + m + 1; incr = NB * 6; }
    else             { optr = dummy + (blockIdx.x * 64 + L);  incr = 0;      }

    float S = 50.0f, G = 10.0f;
    const float2* __restrict__ xf = (const float2*)x;

    float2 A[10], B[10], C[10];
#pragma unroll
    for (int j = 0; j < 10; ++j) A[j] = xf[j * NB + b];
#pragma unroll
    for (int j = 0; j < 10; ++j) B[j] = xf[(10 + j) * NB + b];

    for (int cg = 0; cg < 24; ++cg) {
        const int c0 = 3 * cg;
#pragma unroll
        for (int j = 0; j < 10; ++j) C[j] = xf[((c0 + 2) * 10 + j) * NB + b];
        __builtin_amdgcn_sched_barrier(0);
#pragma unroll
        for (int j = 0; j < 10; ++j) STEPF(A[j]);
#pragma unroll
        for (int j = 0; j < 10; ++j) A[j] = xf[((c0 + 3) * 10 + j) * NB + b];
        __builtin_amdgcn_sched_barrier(0);
#pragma unroll
        for (int j = 0; j < 10; ++j) STEPF(B[j]);
#pragma unroll
        for (int j = 0; j < 10; ++j) {
            int t = (c0 + 4) * 10 + j;
            t = t < T_STEPS ? t : (T_STEPS - 1);
            B[j] = xf[t * NB + b];
        }
        __builtin_amdgcn_sched_barrier(0);
#pragma unroll
        for (int j = 0; j < 10; ++j) STEPF(C[j]);
    }
#pragma unroll
    for (int j = 0; j < 10; ++j) STEPF(A[j]);
}

__global__ __launch_bounds__(256) void uh_fb(const float* __restrict__ raw,
                                             float* __restrict__ uh) {
    int b = blockIdx.x * 256 + threadIdx.x;
    if (b >= NB) return;
    float ra = raw[b * 34 + 32] * 2.9f;
    float rb = raw[b * 34 + 33] * 6.5f;
    float aa = fmaxf(ra, 0.0f) + 0.1f;
    float th = fmaxf(rb, 0.0f) + 0.5f;
    float inv_th = 1.0f / th;
    float am1 = aa - 1.0f;
    float w[LENF];
    float s = 0.0f;
#pragma unroll
    for (int k = 0; k < LENF; ++k) {
        float t = (float)k + 0.5f;
        w[k] = __expf(am1 * __logf(t) - t * inv_th);
        s += w[k];
    }
    float invs = 1.0f / s;
#pragma unroll
    for (int k = 0; k < LENF; ++k) uh[k * NB + b] = w[k] * invs;
}

__global__ __launch_bounds__(256) void conv_fb(const float* __restrict__ qs_ws,
                                               const float* __restrict__ qg_ws,
                                               const float* __restrict__ uh,
                                               float* __restrict__ out) {
    int b = blockIdx.x * 256 + threadIdx.x;
    int t = blockIdx.y;
    if (b >= NB) return;
    float ys = 0.0f, yg = 0.0f;
    int kmax = t < (LENF - 1) ? t : (LENF - 1);
    for (int k = 0; k <= kmax; ++k) {
        float w = uh[k * NB + b];
        ys = fmaf(qs_ws[(t - k) * NB + b], w, ys);
        yg = fmaf(qg_ws[(t - k) * NB + b], w, yg);
    }
    float* o = out + (t * NB + b) * 6;
    o[0] = ys + yg;
    o[1] = ys;
    o[2] = yg;
}

// ===========================================================================
extern "C" void kernel_launch(void* const* d_in, const int* in_sizes, int n_in,
                              void* d_out, int out_size, void* d_ws, size_t ws_size,
                              hipStream_t stream) {
    const float* x   = (const float*)d_in[0];   // (T,B,2) fp32
    const float* raw = (const float*)d_in[1];   // (B,34)  fp32
    float* out = (float*)d_out;                 // (T,B,6) fp32

    const size_t need = (size_t)NLANES * TPAD * 2 * sizeof(float);  // 47.1 MB
    if (ws_size >= need) {
        float* snp = (float*)d_ws;
        float* gnp = snp + (size_t)NLANES * TPAD;
        scan_state<<<dim3((NTHR + 63) / 64), dim3(64),  0, stream>>>(x, raw, snp, gnp);
        finalize  <<<dim3(3, NB),            dim3(256), 0, stream>>>(x, raw, snp, gnp, out);
    } else {
        float* qs = (float*)d_ws;
        float* qg = qs + (size_t)T_STEPS * NB;
        float* uh = qg + (size_t)T_STEPS * NB;
        float* dm = uh + (size_t)LENF * NB;
        uh_fb  <<<dim3((NB + 255) / 256),          dim3(256), 0, stream>>>(raw, uh);
        scan_fb<<<dim3(NB / 8),                    dim3(64),  0, stream>>>(x, raw, out, qs, qg, dm);
        conv_fb<<<dim3((NB + 255) / 256, T_STEPS), dim3(256), 0, stream>>>(qs, qg, uh, out);
    }
}

// Round 2
// 123.198 us; speedup vs baseline: 1.2062x; 1.2062x over previous
//
#include <hip/hip_runtime.h>
#include <math.h>

#define T_STEPS 730
#define NB      1000
#define LENF    15
#define NEARZ   1e-5f
#define SGW     8000           // state width: 1000 basins x 8 members
#define TT      32             // finalize: t-rows per block
#define BBLK    32             // finalize: basins per block

// ===========================================================================
// PASS A: serial S/G recurrence, state planes TRANSPOSED to [t][lane].
// R11 post-mortem: [lane][t] layout made every store hit 64 distinct cache
// lines per wave (row stride 2.9KB) -> VMEM addr-pipe backpressure was the
// unfillable ~110cy/step wave-level stall (C=2 in-wave ILP couldn't touch
// it).  [t][lane] layout: one float2 (Sn,Gn) store per step = 512B
// contiguous per wave (8 full lines).  No rings, no float4 assembly.
// Per step: 13 VALU physics + 1 dwordx2 store + ~2 addr.
// ===========================================================================
#define STEPA(CURV)                                                            \
  {                                                                            \
    float pcp = (CURV).x, pet = (CURV).y;                                      \
    float W     = pcp + S;                                                     \
    float term  = fmaf(W, inv2a, pb2a);                                        \
    float disc  = fmaf(term, term, -(W * boa));                                \
    float r     = __builtin_amdgcn_sqrtf(fmaxf(disc, NEARZ));                  \
    float Y     = term - r;                                                    \
    float e     = __builtin_amdgcn_exp2f(pet * nbl);                           \
    float Sn    = Y * e;                                                       \
    float avail = W - Y;                                                       \
    float Gn    = fmaf(pc, avail, G) * i1d;                                    \
    S = Sn; G = Gn;                                                            \
    *psg = make_float2(Sn, Gn);                                                \
    psg += SGW;                                                                \
  }

#define PREFETCH(BUF, CI)                                                      \
  _Pragma("unroll")                                                            \
  for (int j = 0; j < 8; ++j) {                                                \
      int tt = (CI) * 8 + j;                                                   \
      tt = tt < T_STEPS ? tt : (T_STEPS - 1);                                  \
      BUF[j] = xf[tt * NB + b];                                                \
  }                                                                            \
  __builtin_amdgcn_sched_barrier(0);

__global__ __launch_bounds__(64, 1) void scan_state(const float* __restrict__ x,
                                                    const float* __restrict__ raw,
                                                    float2* __restrict__ sg) {
    const int L   = threadIdx.x;
    const int gid = blockIdx.x * 64 + L;   // 0..7999 (grid=125)
    const int b   = gid >> 3;
    const int m   = gid & 7;

    // raw layout (B,34) = [a(8), b(8), c(8), d(8), ra, rb]
    const float* rp = raw + b * 34;
    float pa = rp[0 * 8 + m] * 0.9f + 0.1f;
    float pb = rp[1 * 8 + m] * 450.0f + 50.0f;
    float pc = rp[2 * 8 + m];
    float pd = rp[3 * 8 + m] * 0.89f + 0.01f;

    float inv2a = 1.0f / (2.0f * pa);
    float pb2a  = pb * inv2a;
    float boa   = pb / pa;
    float nbl   = -1.4426950408889634f / pb;   // exp(-pet/b)=exp2(pet*this)
    float i1d   = 1.0f / (1.0f + pd);

    float S = 50.0f, G = 10.0f;
    float2* psg = sg + gid;                    // advances SGW per step

    const float2* __restrict__ xf = (const float2*)x;   // (T,B) of (p,pet)

    float2 A[8], Bb[8], Cc[8];
    PREFETCH(A, 0)
    PREFETCH(Bb, 1)

    // 15 groups x 48 steps (6 chunks of 8) = 720 steps, + 10-step tail.
    for (int g = 0; g < 15; ++g) {
        const int c0 = 6 * g;
        PREFETCH(Cc, c0 + 2)
#pragma unroll
        for (int j = 0; j < 8; ++j) STEPA(A[j])
        PREFETCH(A, c0 + 3)
#pragma unroll
        for (int j = 0; j < 8; ++j) STEPA(Bb[j])
        PREFETCH(Bb, c0 + 4)
#pragma unroll
        for (int j = 0; j < 8; ++j) STEPA(Cc[j])
        PREFETCH(Cc, c0 + 5)
#pragma unroll
        for (int j = 0; j < 8; ++j) STEPA(A[j])
        PREFETCH(A, c0 + 6)
#pragma unroll
        for (int j = 0; j < 8; ++j) STEPA(Bb[j])
        PREFETCH(Bb, c0 + 7)
#pragma unroll
        for (int j = 0; j < 8; ++j) STEPA(Cc[j])
    }
    // tail: A = chunk 90 (t=720..727), Bb[0]=728, Bb[1]=729
#pragma unroll
    for (int j = 0; j < 8; ++j) STEPA(A[j])
    STEPA(Bb[0])
    STEPA(Bb[1])
}

// ===========================================================================
// 8-lane butterfly reduction (groups of 8 consecutive lanes = one basin).
// ===========================================================================
template <int CTRL>
__device__ __forceinline__ float dpp_mov(float x) {
    int xi = __builtin_bit_cast(int, x);
    int r  = __builtin_amdgcn_update_dpp(0, xi, CTRL, 0xF, 0xF, true);
    return __builtin_bit_cast(float, r);
}
__device__ __forceinline__ float sum8(float v) {
    v += dpp_mov<0xB1>(v);    // quad swap-pairs  (xor 1)
    v += dpp_mov<0x4E>(v);    // quad swap-halves (xor 2)
    v += dpp_mov<0x141>(v);   // row half-mirror  (xor across quads in 8-group)
    return v;
}

// ===========================================================================
// PASS B: t-parallel finalize on [t][lane] planes.
// Block = 256 thr = 32 basins x 8 members; grid (ceil(730/TT)=23, 32).
// Serial t-loop over TT+14 rows (halo): one coalesced 2KB float2 row load
// per step, S[t-1] carried in a register, 8-lane DPP reduce for the 5
// cross-member sums, qs/qg staged in LDS, then 15-tap gamma-UH conv with
// b-across-lanes coalesced out writes.
// ===========================================================================
__global__ __launch_bounds__(256) void finalize(const float* __restrict__ x,
                                                const float* __restrict__ raw,
                                                const float2* __restrict__ sg,
                                                float* __restrict__ out) {
    __shared__ float qsh[TT + 14][BBLK + 1];
    __shared__ float qgh[TT + 14][BBLK + 1];

    const int tid   = threadIdx.x;
    const int lb    = tid >> 3;          // local basin 0..31
    const int m     = tid & 7;
    const int tbase = blockIdx.x * TT;
    const int b0    = blockIdx.y * BBLK;
    const int b     = b0 + lb;
    const bool bval = b < NB;
    const int bc    = bval ? b : (NB - 1);      // clamped for loads
    const int lane  = bc * 8 + m;               // 0..7999

    const float* rp = raw + bc * 34;
    float pbm = rp[8 + m] * 450.0f + 50.0f;
    float e2s = 1.4426950408889634f / pbm;      // Y = Sn * exp2(pet * e2s)
    float omc = 1.0f - rp[16 + m];
    float dm  = rp[24 + m] * 0.89f + 0.01f;

    const float2* __restrict__ xf = (const float2*)x;

    // ---- serial row loop: TT+14 rows, software-pipelined row load --------
    float Sprev = 50.0f;
    int tt0  = tbase - 14;
    int ttc0 = tt0 < 0 ? 0 : tt0;
    float2 sgv = sg[(size_t)ttc0 * SGW + lane];
    float2 pv  = xf[ttc0 * NB + bc];

    for (int r = 0; r < TT + 14; ++r) {
        const int tt = tbase + r - 14;          // block-uniform
        // prefetch next row (clamped; last prefetch harmless)
        int ttn = tt + 1;
        ttn = ttn < 0 ? 0 : (ttn >= T_STEPS ? T_STEPS - 1 : ttn);
        float2 sgn = sg[(size_t)ttn * SGW + lane];
        float2 pvn = xf[ttn * NB + bc];

        const bool tval = (tt >= 0) && (tt < T_STEPS);   // block-uniform
        float qs = 0.0f, qg = 0.0f, aet = 0.0f, sX = 0.0f, gX = 0.0f;
        if (tval) {
            float sp    = (tt == 0) ? 50.0f : Sprev;
            float y     = sgv.x * __builtin_amdgcn_exp2f(pv.y * e2s);
            float avail = (pv.x + sp) - y;
            qs  = omc * avail;
            qg  = dm * sgv.y;
            aet = y - sgv.x;
            sX  = sgv.x;
            gX  = sgv.y;
        }
        qs = sum8(qs);
        qg = sum8(qg);
        if (m == 0) { qsh[r][lb] = qs; qgh[r][lb] = qg; }
        if (r >= 14 && tval) {                   // own tile: write ch3..5
            float a_s = sum8(aet);
            float s_s = sum8(sX);
            float g_s = sum8(gX);
            if (bval && m < 3) {
                float v = (m == 0) ? a_s : ((m == 1) ? s_s : g_s);
                out[((size_t)tt * NB + b) * 6 + 3 + m] = v * 0.125f;
            }
        }
        Sprev = sgv.x;
        sgv = sgn; pv = pvn;
    }
    __syncthreads();

    // ---- conv phase: threads = (t-slot 0..7) x (basin 0..31) -------------
    const int bl2 = tid & 31;
    const int tl0 = tid >> 5;                   // 0..7
    const int b2  = b0 + bl2;
    if (b2 >= NB) return;

    const float* rp2 = raw + b2 * 34;
    float ra = rp2[32] * 2.9f;
    float rb = rp2[33] * 6.5f;
    float aa = fmaxf(ra, 0.0f) + 0.1f;
    float th = fmaxf(rb, 0.0f) + 0.5f;
    float inv_th = 1.0f / th;
    float am1 = aa - 1.0f;
    float w[LENF];
    float sw = 0.0f;
#pragma unroll
    for (int k = 0; k < LENF; ++k) {
        float tk = (float)k + 0.5f;
        w[k] = __expf(am1 * __logf(tk) - tk * inv_th);
        sw += w[k];
    }
    float invs = 0.125f / sw;      // UH normalization x ensemble mean
#pragma unroll
    for (int k = 0; k < LENF; ++k) w[k] *= invs;

#pragma unroll
    for (int it = 0; it < 4; ++it) {
        int tl = tl0 + it * 8;                  // 0..31
        int t  = tbase + tl;
        if (t < T_STEPS) {
            float ys = 0.0f, yg = 0.0f;
#pragma unroll
            for (int k = 0; k < LENF; ++k) {
                ys = fmaf(qsh[tl + 14 - k][bl2], w[k], ys);
                yg = fmaf(qgh[tl + 14 - k][bl2], w[k], yg);
            }
            float* o = out + ((size_t)t * NB + b2) * 6;
            o[0] = ys + yg;
            o[1] = ys;
            o[2] = yg;
        }
    }
}

// ===========================================================================
// FALLBACK (ws too small for the 47MB state planes): R8's proven path.
// ===========================================================================
#define STEPF(CURV)                                                            \
  {                                                                            \
    float pcp = (CURV).x, pet = (CURV).y;                                      \
    float W     = pcp + S;                                                     \
    float term  = fmaf(W, inv2a, pb2a);                                        \
    float disc  = fmaf(term, term, -(W * boa));                                \
    float r     = __builtin_amdgcn_sqrtf(fmaxf(disc, NEARZ));                  \
    float Y     = term - r;                                                    \
    float e     = __builtin_amdgcn_exp2f(pet * ninvbl2);                       \
    float Sn    = Y * e;                                                       \
    float AET   = Y - Sn;                                                      \
    float avail = W - Y;                                                       \
    float Qs    = omc * avail;                                                 \
    float Gn    = fmaf(pc, avail, G) * inv1pd;                                 \
    float Qg    = pd * Gn;                                                     \
    S = Sn; G = Gn;                                                            \
    float qs_s = sum8(Qs);                                                     \
    float qg_s = sum8(Qg);                                                     \
    float ae_s = sum8(AET);                                                    \
    float s_s  = sum8(Sn);                                                     \
    float g_s  = sum8(Gn);                                                     \
    float v = qs_s;                                                            \
    v = (m == 1) ? qg_s : v;                                                   \
    v = (m == 2) ? ae_s : v;                                                   \
    v = (m == 3) ? s_s  : v;                                                   \
    v = (m >= 4) ? g_s  : v;                                                   \
    *optr = v * 0.125f;                                                        \
    optr += incr;                                                              \
  }

__global__ __launch_bounds__(64, 1) void scan_fb(const float* __restrict__ x,
                                                 const float* __restrict__ raw,
                                                 float* __restrict__ out,
                                                 float* __restrict__ qs_ws,
                                                 float* __restrict__ qg_ws,
                                                 float* __restrict__ dummy) {
    const int L  = threadIdx.x;
    const int lb = L >> 3;
    const int m  = L & 7;
    const int b  = blockIdx.x * 8 + lb;

    const float* rp = raw + b * 34;
    float pa = rp[0 * 8 + m] * 0.9f + 0.1f;
    float pb = rp[1 * 8 + m] * 450.0f + 50.0f;
    float pc = rp[2 * 8 + m];
    float pd = rp[3 * 8 + m] * 0.89f + 0.01f;
    float inv2a   = 1.0f / (2.0f * pa);
    float pb2a    = pb * inv2a;
    float boa     = pb / pa;
    float ninvbl2 = -1.4426950408889634f / pb;
    float omc     = 1.0f - pc;
    float inv1pd  = 1.0f / (1.0f + pd);

    float* optr;
    long long incr;
    if      (m == 0) { optr = qs_ws + b;                      incr = NB;     }
    else if (m == 1) { optr = qg_ws + b;                      incr = NB;     }
    else if (m <= 4) { optr = out + (long long)b * 6 + m + 1; incr = NB * 6; }
    else             { optr = dummy + (blockIdx.x * 64 + L);  incr = 0;      }

    float S = 50.0f, G = 10.0f;
    const float2* __restrict__ xf = (const float2*)x;

    float2 A[10], B[10], C[10];
#pragma unroll
    for (int j = 0; j < 10; ++j) A[j] = xf[j * NB + b];
#pragma unroll
    for (int j = 0; j < 10; ++j) B[j] = xf[(10 + j) * NB + b];

    for (int cg = 0; cg < 24; ++cg) {
        const int c0 = 3 * cg;
#pragma unroll
        for (int j = 0; j < 10; ++j) C[j] = xf[((c0 + 2) * 10 + j) * NB + b];
        __builtin_amdgcn_sched_barrier(0);
#pragma unroll
        for (int j = 0; j < 10; ++j) STEPF(A[j]);
#pragma unroll
        for (int j = 0; j < 10; ++j) A[j] = xf[((c0 + 3) * 10 + j) * NB + b];
        __builtin_amdgcn_sched_barrier(0);
#pragma unroll
        for (int j = 0; j < 10; ++j) STEPF(B[j]);
#pragma unroll
        for (int j = 0; j < 10; ++j) {
            int t = (c0 + 4) * 10 + j;
            t = t < T_STEPS ? t : (T_STEPS - 1);
            B[j] = xf[t * NB + b];
        }
        __builtin_amdgcn_sched_barrier(0);
#pragma unroll
        for (int j = 0; j < 10; ++j) STEPF(C[j]);
    }
#pragma unroll
    for (int j = 0; j < 10; ++j) STEPF(A[j]);
}

__global__ __launch_bounds__(256) void uh_fb(const float* __restrict__ raw,
                                             float* __restrict__ uh) {
    int b = blockIdx.x * 256 + threadIdx.x;
    if (b >= NB) return;
    float ra = raw[b * 34 + 32] * 2.9f;
    float rb = raw[b * 34 + 33] * 6.5f;
    float aa = fmaxf(ra, 0.0f) + 0.1f;
    float th = fmaxf(rb, 0.0f) + 0.5f;
    float inv_th = 1.0f / th;
    float am1 = aa - 1.0f;
    float w[LENF];
    float s = 0.0f;
#pragma unroll
    for (int k = 0; k < LENF; ++k) {
        float t = (float)k + 0.5f;
        w[k] = __expf(am1 * __logf(t) - t * inv_th);
        s += w[k];
    }
    float invs = 1.0f / s;
#pragma unroll
    for (int k = 0; k < LENF; ++k) uh[k * NB + b] = w[k] * invs;
}

__global__ __launch_bounds__(256) void conv_fb(const float* __restrict__ qs_ws,
                                               const float* __restrict__ qg_ws,
                                               const float* __restrict__ uh,
                                               float* __restrict__ out) {
    int b = blockIdx.x * 256 + threadIdx.x;
    int t = blockIdx.y;
    if (b >= NB) return;
    float ys = 0.0f, yg = 0.0f;
    int kmax = t < (LENF - 1) ? t : (LENF - 1);
    for (int k = 0; k <= kmax; ++k) {
        float w = uh[k * NB + b];
        ys = fmaf(qs_ws[(t - k) * NB + b], w, ys);
        yg = fmaf(qg_ws[(t - k) * NB + b], w, yg);
    }
    float* o = out + (t * NB + b) * 6;
    o[0] = ys + yg;
    o[1] = ys;
    o[2] = yg;
}

// ===========================================================================
extern "C" void kernel_launch(void* const* d_in, const int* in_sizes, int n_in,
                              void* d_out, int out_size, void* d_ws, size_t ws_size,
                              hipStream_t stream) {
    const float* x   = (const float*)d_in[0];   // (T,B,2) fp32
    const float* raw = (const float*)d_in[1];   // (B,34)  fp32
    float* out = (float*)d_out;                 // (T,B,6) fp32

    const size_t need = (size_t)T_STEPS * SGW * sizeof(float2);  // 46.7 MB
    if (ws_size >= need) {
        float2* sg = (float2*)d_ws;
        scan_state<<<dim3(SGW / 64), dim3(64),  0, stream>>>(x, raw, sg);
        finalize  <<<dim3((T_STEPS + TT - 1) / TT, (NB + BBLK - 1) / BBLK),
                     dim3(256), 0, stream>>>(x, raw, sg, out);
    } else {
        float* qs = (float*)d_ws;
        float* qg = qs + (size_t)T_STEPS * NB;
        float* uh = qg + (size_t)T_STEPS * NB;
        float* dm = uh + (size_t)LENF * NB;
        uh_fb  <<<dim3((NB + 255) / 256),          dim3(256), 0, stream>>>(raw, uh);
        scan_fb<<<dim3(NB / 8),                    dim3(64),  0, stream>>>(x, raw, out, qs, qg, dm);
        conv_fb<<<dim3((NB + 255) / 256, T_STEPS), dim3(256), 0, stream>>>(qs, qg, uh, out);
    }
}

// Round 3
// 113.579 us; speedup vs baseline: 1.3083x; 1.0847x over previous
//
#include <hip/hip_runtime.h>
#include <math.h>

#define T_STEPS 730
#define NB      1000
#define LENF    15
#define NEARZ   1e-5f
#define SGW     8000           // state width: 1000 basins x 8 members
#define TT      50             // finalize: t-rows per block (64 rows incl halo)
#define BBLK    32             // finalize: basins per block

// ===========================================================================
// PASS A: serial S/G recurrence, state [t][lane], forcing staged in LDS.
// R12 theory: loads and stores share the vmcnt FIFO -> every compiler
// s_waitcnt before a prefetched-x use also drained the per-step stores.
// Staging x in LDS moves loop loads to lgkmcnt (ds_read), fully decoupled
// from the store queue: the steady-state loop has NO global loads and NO
// vmcnt waits.  One-time LDS fill: 46 float4 per lane (x for this block's
// 8 basins, all 730 steps, rows 730..735 duplicated), ~46KB LDS, 1 blk/CU.
// Per step: 13 VALU physics + 1 ds_read (amortized) + 1 dwordx2 store + 2 addr.
// ===========================================================================
#define STEPA(CURV)                                                            \
  {                                                                            \
    float pcp = (CURV).x, pet = (CURV).y;                                      \
    float W     = pcp + S;                                                     \
    float term  = fmaf(W, inv2a, pb2a);                                        \
    float disc  = fmaf(term, term, -(W * boa));                                \
    float r     = __builtin_amdgcn_sqrtf(fmaxf(disc, NEARZ));                  \
    float Y     = term - r;                                                    \
    float e     = __builtin_amdgcn_exp2f(pet * nbl);                           \
    float Sn    = Y * e;                                                       \
    float avail = W - Y;                                                       \
    float Gn    = fmaf(pc, avail, G) * i1d;                                    \
    S = Sn; G = Gn;                                                            \
    *psg = make_float2(Sn, Gn);                                                \
    psg += SGW;                                                                \
  }

// LDS prefetch: rows up to 735 are valid (duplicates of 729) -> no clamp.
#define PREFETCH(BUF, CI)                                                      \
  _Pragma("unroll")                                                            \
  for (int j = 0; j < 8; ++j) {                                                \
      BUF[j] = xs[((CI) * 8 + j) * 8 + bl];                                    \
  }                                                                            \
  __builtin_amdgcn_sched_barrier(0);

__global__ __launch_bounds__(64, 1) void scan_state(const float* __restrict__ x,
                                                    const float* __restrict__ raw,
                                                    float2* __restrict__ sg) {
    __shared__ float4 xs4[2944];               // 736 rows x 8 basins x float2
    const float2* xs = (const float2*)xs4;

    const int L   = threadIdx.x;
    const int gid = blockIdx.x * 64 + L;       // 0..7999 (grid=125)
    const int b   = gid >> 3;
    const int m   = gid & 7;
    const int bl  = L >> 3;                    // basin-local 0..7

    // ---- one-time cooperative x -> LDS stage (all loads before any wait) --
    {
        float4 tmp[46];
#pragma unroll
        for (int ch = 0; ch < 46; ++ch) {
            int idx = ch * 64 + L;             // 0..2943
            int row = idx >> 2;                // t row 0..735
            row = row < T_STEPS ? row : (T_STEPS - 1);
            tmp[ch] = *(const float4*)((const char*)x + (size_t)row * (NB * 8)
                                       + (size_t)(blockIdx.x * 64)
                                       + (size_t)(idx & 3) * 16);
        }
#pragma unroll
        for (int ch = 0; ch < 46; ++ch) xs4[ch * 64 + L] = tmp[ch];
    }
    __syncthreads();

    // raw layout (B,34) = [a(8), b(8), c(8), d(8), ra, rb]
    const float* rp = raw + b * 34;
    float pa = rp[0 * 8 + m] * 0.9f + 0.1f;
    float pb = rp[1 * 8 + m] * 450.0f + 50.0f;
    float pc = rp[2 * 8 + m];
    float pd = rp[3 * 8 + m] * 0.89f + 0.01f;

    float inv2a = 1.0f / (2.0f * pa);
    float pb2a  = pb * inv2a;
    float boa   = pb / pa;
    float nbl   = -1.4426950408889634f / pb;   // exp(-pet/b)=exp2(pet*this)
    float i1d   = 1.0f / (1.0f + pd);

    float S = 50.0f, G = 10.0f;
    float2* psg = sg + gid;                    // advances SGW per step

    float2 A[8], Bb[8], Cc[8];
    PREFETCH(A, 0)
    PREFETCH(Bb, 1)

    // 15 groups x 48 steps (6 chunks of 8) = 720 steps, + 10-step tail.
    for (int g = 0; g < 15; ++g) {
        const int c0 = 6 * g;
        PREFETCH(Cc, c0 + 2)
#pragma unroll
        for (int j = 0; j < 8; ++j) STEPA(A[j])
        PREFETCH(A, c0 + 3)
#pragma unroll
        for (int j = 0; j < 8; ++j) STEPA(Bb[j])
        PREFETCH(Bb, c0 + 4)
#pragma unroll
        for (int j = 0; j < 8; ++j) STEPA(Cc[j])
        PREFETCH(Cc, c0 + 5)
#pragma unroll
        for (int j = 0; j < 8; ++j) STEPA(A[j])
        PREFETCH(A, c0 + 6)
#pragma unroll
        for (int j = 0; j < 8; ++j) STEPA(Bb[j])
        PREFETCH(Bb, c0 + 7)
#pragma unroll
        for (int j = 0; j < 8; ++j) STEPA(Cc[j])
    }
    // tail: A = rows 720..727, Bb[0]=728, Bb[1]=729
#pragma unroll
    for (int j = 0; j < 8; ++j) STEPA(A[j])
    STEPA(Bb[0])
    STEPA(Bb[1])
}

// ===========================================================================
// 8-lane butterfly reduction (groups of 8 consecutive lanes = one basin).
// ===========================================================================
template <int CTRL>
__device__ __forceinline__ float dpp_mov(float x) {
    int xi = __builtin_bit_cast(int, x);
    int r  = __builtin_amdgcn_update_dpp(0, xi, CTRL, 0xF, 0xF, true);
    return __builtin_bit_cast(float, r);
}
__device__ __forceinline__ float sum8(float v) {
    v += dpp_mov<0xB1>(v);    // xor 1
    v += dpp_mov<0x4E>(v);    // xor 2
    v += dpp_mov<0x141>(v);   // xor 4 within 8-group
    return v;
}

// ===========================================================================
// PASS B: t-parallel finalize on [t][lane] planes.
// Block = 256 thr = 32 basins x 8 members; grid (ceil(730/TT)=15, 32).
// 4-deep software-pipelined row loop over TT+14=64 rows; S[t-1] carried in
// a register (halo-seeded from sg[tbase-15] -- R12 fix: R2 seeded 50.0 for
// non-first tiles, wrong at the oldest conv tap); 8-lane DPP reduce; qs/qg
// staged in LDS; 15-tap gamma-UH conv with b-across-lanes coalesced writes.
// ===========================================================================
__global__ __launch_bounds__(256) void finalize(const float* __restrict__ x,
                                                const float* __restrict__ raw,
                                                const float2* __restrict__ sg,
                                                float* __restrict__ out) {
    __shared__ float qsh[TT + 14][BBLK + 1];
    __shared__ float qgh[TT + 14][BBLK + 1];

    const int tid   = threadIdx.x;
    const int lb    = tid >> 3;          // local basin 0..31
    const int m     = tid & 7;
    const int tbase = blockIdx.x * TT;
    const int b0    = blockIdx.y * BBLK;
    const int b     = b0 + lb;
    const bool bval = b < NB;
    const int bc    = bval ? b : (NB - 1);      // clamped for loads
    const int lane  = bc * 8 + m;               // 0..7999

    const float* rp = raw + bc * 34;
    float pbm = rp[8 + m] * 450.0f + 50.0f;
    float e2s = 1.4426950408889634f / pbm;      // Y = Sn * exp2(pet * e2s)
    float omc = 1.0f - rp[16 + m];
    float dm  = rp[24 + m] * 0.89f + 0.01f;

    const float2* __restrict__ xf = (const float2*)x;

    // ---- 4-deep pipelined row loop: 64 rows ------------------------------
    float2 sgb[4], pvb[4];
#pragma unroll
    for (int d = 0; d < 4; ++d) {
        int tt = tbase + d - 14;
        int tc = tt < 0 ? 0 : (tt >= T_STEPS ? T_STEPS - 1 : tt);
        sgb[d] = sg[(size_t)tc * SGW + lane];
        pvb[d] = xf[tc * NB + bc];
    }
    float Sprev = (tbase > 0) ? sg[(size_t)(tbase - 15) * SGW + lane].x : 50.0f;

    for (int rr = 0; rr < TT + 14; rr += 4) {
#pragma unroll
        for (int d = 0; d < 4; ++d) {
            const int r  = rr + d;
            const int tt = tbase + r - 14;          // block-uniform
            float2 sgv = sgb[d];
            float2 pv  = pvb[d];
            {   // issue row r+4 load (clamped; tail loads harmless)
                int tn = tt + 4;
                int tc = tn < 0 ? 0 : (tn >= T_STEPS ? T_STEPS - 1 : tn);
                sgb[d] = sg[(size_t)tc * SGW + lane];
                pvb[d] = xf[tc * NB + bc];
            }
            const bool tval = (tt >= 0) && (tt < T_STEPS);
            float qs = 0.0f, qg = 0.0f, aet = 0.0f, sX = 0.0f, gX = 0.0f;
            if (tval) {
                float sp    = (tt == 0) ? 50.0f : Sprev;
                float y     = sgv.x * __builtin_amdgcn_exp2f(pv.y * e2s);
                float avail = (pv.x + sp) - y;
                qs  = omc * avail;
                qg  = dm * sgv.y;
                aet = y - sgv.x;
                sX  = sgv.x;
                gX  = sgv.y;
            }
            qs = sum8(qs);
            qg = sum8(qg);
            if (m == 0) { qsh[r][lb] = qs; qgh[r][lb] = qg; }
            if (r >= 14 && tval) {                   // own tile: ch3..5
                float a_s = sum8(aet);
                float s_s = sum8(sX);
                float g_s = sum8(gX);
                if (bval && m < 3) {
                    float v = (m == 0) ? a_s : ((m == 1) ? s_s : g_s);
                    out[((size_t)tt * NB + b) * 6 + 3 + m] = v * 0.125f;
                }
            }
            Sprev = sgv.x;
        }
    }
    __syncthreads();

    // ---- conv phase: threads = (t-slot 0..7) x (basin 0..31) -------------
    const int bl2 = tid & 31;
    const int tl0 = tid >> 5;                   // 0..7
    const int b2  = b0 + bl2;
    if (b2 >= NB) return;

    const float* rp2 = raw + b2 * 34;
    float ra = rp2[32] * 2.9f;
    float rb = rp2[33] * 6.5f;
    float aa = fmaxf(ra, 0.0f) + 0.1f;
    float th = fmaxf(rb, 0.0f) + 0.5f;
    float inv_th = 1.0f / th;
    float am1 = aa - 1.0f;
    float w[LENF];
    float sw = 0.0f;
#pragma unroll
    for (int k = 0; k < LENF; ++k) {
        float tk = (float)k + 0.5f;
        w[k] = __expf(am1 * __logf(tk) - tk * inv_th);
        sw += w[k];
    }
    float invs = 0.125f / sw;      // UH normalization x ensemble mean
#pragma unroll
    for (int k = 0; k < LENF; ++k) w[k] *= invs;

#pragma unroll
    for (int it = 0; it < 7; ++it) {
        int tl = tl0 + it * 8;                  // 0..55
        int t  = tbase + tl;
        if (tl < TT && t < T_STEPS) {
            float ys = 0.0f, yg = 0.0f;
#pragma unroll
            for (int k = 0; k < LENF; ++k) {
                ys = fmaf(qsh[tl + 14 - k][bl2], w[k], ys);
                yg = fmaf(qgh[tl + 14 - k][bl2], w[k], yg);
            }
            float* o = out + ((size_t)t * NB + b2) * 6;
            o[0] = ys + yg;
            o[1] = ys;
            o[2] = yg;
        }
    }
}

// ===========================================================================
// FALLBACK (ws too small for the 47MB state plane): R8's proven path.
// ===========================================================================
#define STEPF(CURV)                                                            \
  {                                                                            \
    float pcp = (CURV).x, pet = (CURV).y;                                      \
    float W     = pcp + S;                                                     \
    float term  = fmaf(W, inv2a, pb2a);                                        \
    float disc  = fmaf(term, term, -(W * boa));                                \
    float r     = __builtin_amdgcn_sqrtf(fmaxf(disc, NEARZ));                  \
    float Y     = term - r;                                                    \
    float e     = __builtin_amdgcn_exp2f(pet * ninvbl2);                       \
    float Sn    = Y * e;                                                       \
    float AET   = Y - Sn;                                                      \
    float avail = W - Y;                                                       \
    float Qs    = omc * avail;                                                 \
    float Gn    = fmaf(pc, avail, G) * inv1pd;                                 \
    float Qg    = pd * Gn;                                                     \
    S = Sn; G = Gn;                                                            \
    float qs_s = sum8(Qs);                                                     \
    float qg_s = sum8(Qg);                                                     \
    float ae_s = sum8(AET);                                                    \
    float s_s  = sum8(Sn);                                                     \
    float g_s  = sum8(Gn);                                                     \
    float v = qs_s;                                                            \
    v = (m == 1) ? qg_s : v;                                                   \
    v = (m == 2) ? ae_s : v;                                                   \
    v = (m == 3) ? s_s  : v;                                                   \
    v = (m >= 4) ? g_s  : v;                                                   \
    *optr = v * 0.125f;                                                        \
    optr += incr;                                                              \
  }

__global__ __launch_bounds__(64, 1) void scan_fb(const float* __restrict__ x,
                                                 const float* __restrict__ raw,
                                                 float* __restrict__ out,
                                                 float* __restrict__ qs_ws,
                                                 float* __restrict__ qg_ws,
                                                 float* __restrict__ dummy) {
    const int L  = threadIdx.x;
    const int lb = L >> 3;
    const int m  = L & 7;
    const int b  = blockIdx.x * 8 + lb;

    const float* rp = raw + b * 34;
    float pa = rp[0 * 8 + m] * 0.9f + 0.1f;
    float pb = rp[1 * 8 + m] * 450.0f + 50.0f;
    float pc = rp[2 * 8 + m];
    float pd = rp[3 * 8 + m] * 0.89f + 0.01f;
    float inv2a   = 1.0f / (2.0f * pa);
    float pb2a    = pb * inv2a;
    float boa     = pb / pa;
    float ninvbl2 = -1.4426950408889634f / pb;
    float omc     = 1.0f - pc;
    float inv1pd  = 1.0f / (1.0f + pd);

    float* optr;
    long long incr;
    if      (m == 0) { optr = qs_ws + b;                      incr = NB;     }
    else if (m == 1) { optr = qg_ws + b;                      incr = NB;     }
    else if (m <= 4) { optr = out + (long long)b * 6 + m + 1; incr = NB * 6; }
    else             { optr = dummy + (blockIdx.x * 64 + L);  incr = 0;      }

    float S = 50.0f, G = 10.0f;
    const float2* __restrict__ xf = (const float2*)x;

    float2 A[10], B[10], C[10];
#pragma unroll
    for (int j = 0; j < 10; ++j) A[j] = xf[j * NB + b];
#pragma unroll
    for (int j = 0; j < 10; ++j) B[j] = xf[(10 + j) * NB + b];

    for (int cg = 0; cg < 24; ++cg) {
        const int c0 = 3 * cg;
#pragma unroll
        for (int j = 0; j < 10; ++j) C[j] = xf[((c0 + 2) * 10 + j) * NB + b];
        __builtin_amdgcn_sched_barrier(0);
#pragma unroll
        for (int j = 0; j < 10; ++j) STEPF(A[j]);
#pragma unroll
        for (int j = 0; j < 10; ++j) A[j] = xf[((c0 + 3) * 10 + j) * NB + b];
        __builtin_amdgcn_sched_barrier(0);
#pragma unroll
        for (int j = 0; j < 10; ++j) STEPF(B[j]);
#pragma unroll
        for (int j = 0; j < 10; ++j) {
            int t = (c0 + 4) * 10 + j;
            t = t < T_STEPS ? t : (T_STEPS - 1);
            B[j] = xf[t * NB + b];
        }
        __builtin_amdgcn_sched_barrier(0);
#pragma unroll
        for (int j = 0; j < 10; ++j) STEPF(C[j]);
    }
#pragma unroll
    for (int j = 0; j < 10; ++j) STEPF(A[j]);
}

__global__ __launch_bounds__(256) void uh_fb(const float* __restrict__ raw,
                                             float* __restrict__ uh) {
    int b = blockIdx.x * 256 + threadIdx.x;
    if (b >= NB) return;
    float ra = raw[b * 34 + 32] * 2.9f;
    float rb = raw[b * 34 + 33] * 6.5f;
    float aa = fmaxf(ra, 0.0f) + 0.1f;
    float th = fmaxf(rb, 0.0f) + 0.5f;
    float inv_th = 1.0f / th;
    float am1 = aa - 1.0f;
    float w[LENF];
    float s = 0.0f;
#pragma unroll
    for (int k = 0; k < LENF; ++k) {
        float t = (float)k + 0.5f;
        w[k] = __expf(am1 * __logf(t) - t * inv_th);
        s += w[k];
    }
    float invs = 1.0f / s;
#pragma unroll
    for (int k = 0; k < LENF; ++k) uh[k * NB + b] = w[k] * invs;
}

__global__ __launch_bounds__(256) void conv_fb(const float* __restrict__ qs_ws,
                                               const float* __restrict__ qg_ws,
                                               const float* __restrict__ uh,
                                               float* __restrict__ out) {
    int b = blockIdx.x * 256 + threadIdx.x;
    int t = blockIdx.y;
    if (b >= NB) return;
    float ys = 0.0f, yg = 0.0f;
    int kmax = t < (LENF - 1) ? t : (LENF - 1);
    for (int k = 0; k <= kmax; ++k) {
        float w = uh[k * NB + b];
        ys = fmaf(qs_ws[(t - k) * NB + b], w, ys);
        yg = fmaf(qg_ws[(t - k) * NB + b], w, yg);
    }
    float* o = out + (t * NB + b) * 6;
    o[0] = ys + yg;
    o[1] = ys;
    o[2] = yg;
}

// ===========================================================================
extern "C" void kernel_launch(void* const* d_in, const int* in_sizes, int n_in,
                              void* d_out, int out_size, void* d_ws, size_t ws_size,
                              hipStream_t stream) {
    const float* x   = (const float*)d_in[0];   // (T,B,2) fp32
    const float* raw = (const float*)d_in[1];   // (B,34)  fp32
    float* out = (float*)d_out;                 // (T,B,6) fp32

    const size_t need = (size_t)T_STEPS * SGW * sizeof(float2);  // 46.7 MB
    if (ws_size >= need) {
        float2* sg = (float2*)d_ws;
        scan_state<<<dim3(SGW / 64), dim3(64),  0, stream>>>(x, raw, sg);
        finalize  <<<dim3((T_STEPS + TT - 1) / TT, (NB + BBLK - 1) / BBLK),
                     dim3(256), 0, stream>>>(x, raw, sg, out);
    } else {
        float* qs = (float*)d_ws;
        float* qg = qs + (size_t)T_STEPS * NB;
        float* uh = qg + (size_t)T_STEPS * NB;
        float* dm = uh + (size_t)LENF * NB;
        uh_fb  <<<dim3((NB + 255) / 256),          dim3(256), 0, stream>>>(raw, uh);
        scan_fb<<<dim3(NB / 8),                    dim3(64),  0, stream>>>(x, raw, out, qs, qg, dm);
        conv_fb<<<dim3((NB + 255) / 256, T_STEPS), dim3(256), 0, stream>>>(qs, qg, uh, out);
    }
}